// Round 6
// baseline (169.791 us; speedup 1.0000x reference)
//
#include <hip/hip_runtime.h>
#include <hip/hip_bf16.h>

// Binarized conv block (XNOR-net style):
//   a  = sign(x + bias1)          in {+1,-1},  sign(0)=+1
//   qk = sign(kernel)             in {+1,-1}
//   y  = conv2d(a, qk, SAME, s=1) NHWC/HWIO, B=32 H=W=56 Cin=Cout=256
//   out = relu((y - mean)*rsqrt(var+eps) + beta + bias2), eps=1e-3
//
// +-1 dot over Cin=256  ==  256 - 2*popcount(xor of 256-bit packed operands).
// Zero-padded [32][58][58][4]-u64 activation array (pad words = 0 bits decode
// as a=-1) + exact per-tap corrections. Corners subtract the overlap once.
//
// Pad zeroing by kernel, NOT hipMemsetAsync (memset didn't take effect under
// graph replay — post-timing divergence with 0xAA signature in the pad ring).
//
// R4/R5 lesson: the allocator refuses to keep 36 per-thread weight words
// resident (stuck at 64 VGPR, reloading weights per wx -> 143us, 2.9x floor);
// neither __launch_bounds__ nor asm pins change it. R6 restructure: make the
// 56 OUTPUT ACCUMULATORS the resident state (can't be rematerialized -> the
// allocator must keep them), stream weights (36 coalesced loads per 56
// outputs), and broadcast activations from LDS (wave-uniform ds_read_b64,
// conflict-free, immediate offsets). Sliding window: each staged word read
// once per (ky,c); exactly 3x56 xor+popc pairs per (ky,c) = essential VALU.

#define B   32
#define HW  56
#define HP  58          // padded spatial dim
#define CIN 256
#define COUT 256
#define CHUNKS 4        // 256 bits = 4 x u64
#define ROWW (HP * CHUNKS)      // 232 u64 per padded row
#define STAGE (3 * ROWW)        // 696 u64 = 5568 B staged per block

typedef unsigned long long u64;

// ---------------- zero the padded activation array ----------------
__global__ __launch_bounds__(256) void zero_pa_kernel(u64* __restrict__ pa)
{
    const size_t i = (size_t)blockIdx.x * 256 + threadIdx.x;
    pa[i] = 0ull;        // grid sized to cover exactly B*HP*HP*CHUNKS
}

// ---------------- pack activations: x + bias1 -> sign bits ----------------
__global__ __launch_bounds__(256) void pack_a_kernel(
    const float* __restrict__ x, const float* __restrict__ b1,
    u64* __restrict__ pa)
{
    const int wave = threadIdx.x >> 6;
    const int lane = threadIdx.x & 63;
    const int pixel = blockIdx.x * 4 + wave;          // grid covers exactly B*HW*HW
    const int n = pixel / (HW * HW);
    const int rem = pixel % (HW * HW);
    const int h = rem / HW, w = rem % HW;

    const float* xp = x + (size_t)pixel * CIN;
    const size_t po = (((size_t)n * HP + (h + 1)) * HP + (w + 1)) * CHUNKS;
#pragma unroll
    for (int c = 0; c < CHUNKS; ++c) {
        const int ch = c * 64 + lane;
        const u64 m = __ballot(xp[ch] + b1[ch] >= 0.0f);
        if (lane == 0) pa[po + c] = m;
    }
}

// ---------------- pack weights: sign(kernel) -> bits ----------------
// layout pk[tap][chunk][cout] so conv weight loads are coalesced over cout.
__global__ __launch_bounds__(256) void pack_k_kernel(
    const float* __restrict__ k, u64* __restrict__ pk)
{
    const int wave = threadIdx.x >> 6;
    const int lane = threadIdx.x & 63;
    const int idx = blockIdx.x * 4 + wave;            // 0 .. 9*COUT-1
    const int tap = idx >> 8;
    const int cout = idx & 255;
#pragma unroll
    for (int c = 0; c < CHUNKS; ++c) {
        const int cin = c * 64 + lane;
        const float v = k[((size_t)tap * CIN + cin) * COUT + cout];
        const u64 m = __ballot(v >= 0.0f);
        if (lane == 0) pk[((size_t)tap * CHUNKS + c) * COUT + cout] = m;
    }
}

// ---------------- binarized conv + BN + bias + relu ----------------
// block = 256 threads; thread t <-> cout t; block <-> one (n,h) output row.
// acc[56] resident in VGPRs; weights streamed (3 coalesced loads per (ky,c));
// activations broadcast from LDS. Stores coalesced over cout.
__global__ __launch_bounds__(256, 5) void conv_bin_kernel(
    const u64* __restrict__ pa, const u64* __restrict__ pk,
    const float* __restrict__ beta, const float* __restrict__ mean,
    const float* __restrict__ var, const float* __restrict__ bias2,
    float* __restrict__ out)
{
    const int t  = threadIdx.x;          // cout
    const int bh = blockIdx.x;           // n*HW + h
    const int n  = bh / HW, h = bh % HW;

    // stage 3 padded rows (contiguous in pa) into LDS
    __shared__ u64 arow[STAGE];
    const u64* src = pa + ((size_t)(n * HP + h)) * ROWW;
    for (int i = t; i < STAGE; i += 256) arow[i] = src[i];
    __syncthreads();

    // folded BN + bias2:  out = relu(y*s + tt)
    const float s  = 1.0f / sqrtf(var[t] + 1e-3f);
    const float tt = beta[t] - mean[t] * s + bias2[t];

    int acc[HW];
#pragma unroll
    for (int i = 0; i < HW; ++i) acc[i] = 0;

    // streaming popcount accumulators for edge corrections
    int PL = 0, PR = 0, PT = 0, PB = 0;
    int P00 = 0, P02 = 0, P20 = 0, P22 = 0;

#pragma unroll 1
    for (int kc = 0; kc < 12; ++kc) {    // kc = ky*4 + c, kept rolled
        const int ky = kc >> 2;
        const int c  = kc & 3;

        const u64 wv0 = pk[((size_t)(3 * ky + 0) * CHUNKS + c) * COUT + t];
        const u64 wv1 = pk[((size_t)(3 * ky + 1) * CHUNKS + c) * COUT + t];
        const u64 wv2 = pk[((size_t)(3 * ky + 2) * CHUNKS + c) * COUT + t];

        const int t0 = __popcll(wv0), t1 = __popcll(wv1), t2 = __popcll(wv2);
        PL += t0; PR += t2;
        if (kc < 4)  { PT += t0 + t1 + t2; P00 += t0; P02 += t2; }   // ky==0
        if (kc >= 8) { PB += t0 + t1 + t2; P20 += t0; P22 += t2; }   // ky==2

        const u64* row = arow + ky * ROWW + c;     // stride CHUNKS per col
#pragma unroll
        for (int p = 0; p < HP; ++p) {
            const u64 v = row[p * CHUNKS];
            if (p < HW)               acc[p]     += __popcll(v ^ wv0);  // kx=0
            if (p >= 1 && p - 1 < HW) acc[p - 1] += __popcll(v ^ wv1);  // kx=1
            if (p >= 2)               acc[p - 2] += __popcll(v ^ wv2);  // kx=2
        }
    }

    // edge corrections (verified scheme: pcw[tap] = CIN - 2*S[tap]; corners once)
    const bool top = (h == 0), bot = (h == HW - 1);
    const int cLfull = 3 * CIN - 2 * PL;           // sum_ky pcw[ky][0]
    const int cRfull = 3 * CIN - 2 * PR;           // sum_ky pcw[ky][2]
    const int cTrow  = top ? (3 * CIN - 2 * PT) : 0;
    const int cBrow  = bot ? (3 * CIN - 2 * PB) : 0;
    const int oL = (top ? (CIN - 2 * P00) : 0) + (bot ? (CIN - 2 * P20) : 0);
    const int oR = (top ? (CIN - 2 * P02) : 0) + (bot ? (CIN - 2 * P22) : 0);
    const int cL = cLfull - oL;
    const int cR = cRfull - oR;
    const int cbase = cTrow + cBrow;

    float* op = out + (size_t)bh * HW * COUT + t;
#pragma unroll
    for (int wx = 0; wx < HW; ++wx) {
        const int corr = cbase + (wx == 0 ? cL : 0) + (wx == HW - 1 ? cR : 0);
        const float y = (float)(9 * CIN - 2 * acc[wx] - corr);
        op[(size_t)wx * COUT] = fmaxf(fmaf(y, s, tt), 0.0f);
    }
}

extern "C" void kernel_launch(void* const* d_in, const int* in_sizes, int n_in,
                              void* d_out, int out_size, void* d_ws, size_t ws_size,
                              hipStream_t stream)
{
    const float* x      = (const float*)d_in[0];
    const float* bias1  = (const float*)d_in[1];
    const float* kernel = (const float*)d_in[2];
    const float* bn_beta = (const float*)d_in[3];
    const float* bn_mean = (const float*)d_in[4];
    const float* bn_var  = (const float*)d_in[5];
    const float* bias2   = (const float*)d_in[6];
    float* out = (float*)d_out;

    u64* pa = (u64*)d_ws;                                  // padded packed activations
    const size_t pa_elems = (size_t)B * HP * HP * CHUNKS;  // 430,592 u64 = 3.44 MB
    u64* pk = pa + pa_elems;                               // packed weights, 9216 u64

    // zero the padded activation array with a kernel (graph-capture safe)
    zero_pa_kernel<<<dim3((int)(pa_elems / 256)), dim3(256), 0, stream>>>(pa);

    const int npix = B * HW * HW;                          // 100352
    pack_a_kernel<<<dim3(npix / 4), dim3(256), 0, stream>>>(x, bias1, pa);
    pack_k_kernel<<<dim3(9 * COUT / 4), dim3(256), 0, stream>>>(kernel, pk);
    conv_bin_kernel<<<dim3(B * HW), dim3(256), 0, stream>>>(
        pa, pk, bn_beta, bn_mean, bn_var, bias2, out);
}

// Round 7
// 167.452 us; speedup vs baseline: 1.0140x; 1.0140x over previous
//
#include <hip/hip_runtime.h>
#include <hip/hip_bf16.h>

// Binarized conv block (XNOR-net style):
//   a  = sign(x + bias1)  in {+1,-1};  qk = sign(kernel)
//   y  = conv2d(a, qk, SAME, s=1) NHWC/HWIO, B=32 H=W=56 Cin=Cout=256
//   out = relu((y - mean)*rsqrt(var+eps) + beta + bias2), eps=1e-3
//
// +-1 dot over Cin=256 == 256 - 2*popcount(xor of 256-bit packed operands).
// Zero-padded [32][58][58][4]-u64 activation array (pad words = 0 bits decode
// as a=-1) + exact per-tap corrections. Corners subtract the overlap once.
//
// Pad zeroing by kernel, NOT hipMemsetAsync (memset didn't take effect under
// graph replay — post-timing divergence with 0xAA signature in the pad ring).
//
// R4-R6 lesson: hipcc's register-budget heuristic on this kernel settles at
// ~48-64 VGPRs and spills any per-thread array beyond it (w[36]: reloaded per
// iter; acc[56]: VGPR_Count=48 < 56 -> scratch/AGPR shuffle, 2.5x VALU).
// R7: shrink resident state BELOW the budget: 28 outputs per thread
// (2 blocks per output row). acc[28]+weights+window ~ 60 VGPRs.

#define B   32
#define HW  56
#define HP  58          // padded spatial dim
#define CIN 256
#define COUT 256
#define CHUNKS 4        // 256 bits = 4 x u64
#define OW   28         // outputs per block (half row)
#define WIN  30         // staged window positions = OW + 2

typedef unsigned long long u64;

// ---------------- zero the padded activation array ----------------
__global__ __launch_bounds__(256) void zero_pa_kernel(u64* __restrict__ pa)
{
    const size_t i = (size_t)blockIdx.x * 256 + threadIdx.x;
    pa[i] = 0ull;        // grid sized to cover exactly B*HP*HP*CHUNKS
}

// ---------------- pack activations: x + bias1 -> sign bits ----------------
__global__ __launch_bounds__(256) void pack_a_kernel(
    const float* __restrict__ x, const float* __restrict__ b1,
    u64* __restrict__ pa)
{
    const int wave = threadIdx.x >> 6;
    const int lane = threadIdx.x & 63;
    const int pixel = blockIdx.x * 4 + wave;          // grid covers exactly B*HW*HW
    const int n = pixel / (HW * HW);
    const int rem = pixel % (HW * HW);
    const int h = rem / HW, w = rem % HW;

    const float* xp = x + (size_t)pixel * CIN;
    const size_t po = (((size_t)n * HP + (h + 1)) * HP + (w + 1)) * CHUNKS;
#pragma unroll
    for (int c = 0; c < CHUNKS; ++c) {
        const int ch = c * 64 + lane;
        const u64 m = __ballot(xp[ch] + b1[ch] >= 0.0f);
        if (lane == 0) pa[po + c] = m;
    }
}

// ---------------- pack weights: sign(kernel) -> bits ----------------
// layout pk[tap][chunk][cout] so conv weight loads are coalesced over cout.
__global__ __launch_bounds__(256) void pack_k_kernel(
    const float* __restrict__ k, u64* __restrict__ pk)
{
    const int wave = threadIdx.x >> 6;
    const int lane = threadIdx.x & 63;
    const int idx = blockIdx.x * 4 + wave;            // 0 .. 9*COUT-1
    const int tap = idx >> 8;
    const int cout = idx & 255;
#pragma unroll
    for (int c = 0; c < CHUNKS; ++c) {
        const int cin = c * 64 + lane;
        const float v = k[((size_t)tap * CIN + cin) * COUT + cout];
        const u64 m = __ballot(v >= 0.0f);
        if (lane == 0) pk[((size_t)tap * CHUNKS + c) * COUT + cout] = m;
    }
}

// ---------------- binarized conv + BN + bias + relu ----------------
// block = 256 threads; thread t <-> cout t; block <-> half of one (n,h) row.
// acc[28] resident in VGPRs; weights streamed (3 coalesced loads per (ky,c));
// activations broadcast from LDS (wave-uniform, conflict-free).
__global__ __launch_bounds__(256, 4) void conv_bin_kernel(
    const u64* __restrict__ pa, const u64* __restrict__ pk,
    const float* __restrict__ beta, const float* __restrict__ mean,
    const float* __restrict__ var, const float* __restrict__ bias2,
    float* __restrict__ out)
{
    const int t    = threadIdx.x;        // cout
    const int bid  = blockIdx.x;         // (n*HW + h)*2 + half
    const int half = bid & 1;
    const int nh   = bid >> 1;           // n*HW + h
    const int n    = nh / HW, h = nh % HW;
    const int wx0  = half * OW;          // first output col of this block

    // stage 3 padded rows x WIN positions into LDS (each row seg contiguous)
    __shared__ u64 arow[3][WIN * CHUNKS];
    {
        const u64* src = pa + (((size_t)n * HP + h) * HP + wx0) * CHUNKS;
        for (int i = t; i < 3 * WIN * CHUNKS; i += 256) {
            const int r = i / (WIN * CHUNKS), j = i % (WIN * CHUNKS);
            arow[r][j] = src[(size_t)r * HP * CHUNKS + j];
        }
    }
    __syncthreads();

    // folded BN + bias2:  out = relu(y*s + tt)
    const float s  = 1.0f / sqrtf(var[t] + 1e-3f);
    const float tt = beta[t] - mean[t] * s + bias2[t];

    int acc[OW];
#pragma unroll
    for (int i = 0; i < OW; ++i) acc[i] = 0;

    // streaming popcount accumulators for edge corrections
    int PL = 0, PR = 0, PT = 0, PB = 0;
    int P00 = 0, P02 = 0, P20 = 0, P22 = 0;

#pragma unroll 1
    for (int kc = 0; kc < 12; ++kc) {    // kc = ky*4 + c, kept rolled
        const int ky = kc >> 2;
        const int c  = kc & 3;

        const u64 wv0 = pk[((size_t)(3 * ky + 0) * CHUNKS + c) * COUT + t];
        const u64 wv1 = pk[((size_t)(3 * ky + 1) * CHUNKS + c) * COUT + t];
        const u64 wv2 = pk[((size_t)(3 * ky + 2) * CHUNKS + c) * COUT + t];

        const int t0 = __popcll(wv0), t1 = __popcll(wv1), t2 = __popcll(wv2);
        PL += t0; PR += t2;
        if (kc < 4)  { PT += t0 + t1 + t2; P00 += t0; P02 += t2; }   // ky==0
        if (kc >= 8) { PB += t0 + t1 + t2; P20 += t0; P22 += t2; }   // ky==2

        const u64* row = &arow[ky][c];             // stride CHUNKS per position
#pragma unroll
        for (int p = 0; p < WIN; ++p) {
            const u64 v = row[p * CHUNKS];
            // staged position p = output o + kx  ->  o = p - kx
            if (p < OW)                acc[p]     += __popcll(v ^ wv0);  // kx=0
            if (p >= 1 && p - 1 < OW)  acc[p - 1] += __popcll(v ^ wv1);  // kx=1
            if (p >= 2)                acc[p - 2] += __popcll(v ^ wv2);  // kx=2
        }
    }

    // edge corrections (pcw[tap] = CIN - 2*S[tap]; corner overlap once)
    const bool top = (h == 0), bot = (h == HW - 1);
    const int cTrow = top ? (3 * CIN - 2 * PT) : 0;
    const int cBrow = bot ? (3 * CIN - 2 * PB) : 0;
    const int oL = (top ? (CIN - 2 * P00) : 0) + (bot ? (CIN - 2 * P20) : 0);
    const int oR = (top ? (CIN - 2 * P02) : 0) + (bot ? (CIN - 2 * P22) : 0);
    const int cL = (3 * CIN - 2 * PL) - oL;        // only output wx==0 (half 0, o==0)
    const int cR = (3 * CIN - 2 * PR) - oR;        // only output wx==55 (half 1, o==27)
    const int cbase = cTrow + cBrow;

    float* op = out + (((size_t)nh * HW) + wx0) * COUT + t;
#pragma unroll
    for (int o = 0; o < OW; ++o) {
        int corr = cbase;
        if (half == 0 && o == 0)      corr += cL;
        if (half == 1 && o == OW - 1) corr += cR;
        const float y = (float)(9 * CIN - 2 * acc[o] - corr);
        op[(size_t)o * COUT] = fmaxf(fmaf(y, s, tt), 0.0f);
    }
}

extern "C" void kernel_launch(void* const* d_in, const int* in_sizes, int n_in,
                              void* d_out, int out_size, void* d_ws, size_t ws_size,
                              hipStream_t stream)
{
    const float* x      = (const float*)d_in[0];
    const float* bias1  = (const float*)d_in[1];
    const float* kernel = (const float*)d_in[2];
    const float* bn_beta = (const float*)d_in[3];
    const float* bn_mean = (const float*)d_in[4];
    const float* bn_var  = (const float*)d_in[5];
    const float* bias2   = (const float*)d_in[6];
    float* out = (float*)d_out;

    u64* pa = (u64*)d_ws;                                  // padded packed activations
    const size_t pa_elems = (size_t)B * HP * HP * CHUNKS;  // 430,592 u64 = 3.44 MB
    u64* pk = pa + pa_elems;                               // packed weights, 9216 u64

    // zero the padded activation array with a kernel (graph-capture safe)
    zero_pa_kernel<<<dim3((int)(pa_elems / 256)), dim3(256), 0, stream>>>(pa);

    const int npix = B * HW * HW;                          // 100352
    pack_a_kernel<<<dim3(npix / 4), dim3(256), 0, stream>>>(x, bias1, pa);
    pack_k_kernel<<<dim3(9 * COUT / 4), dim3(256), 0, stream>>>(kernel, pk);
    conv_bin_kernel<<<dim3(B * HW * 2), dim3(256), 0, stream>>>(
        pa, pk, bn_beta, bn_mean, bn_var, bias2, out);
}

// Round 8
// 135.687 us; speedup vs baseline: 1.2513x; 1.2341x over previous
//
#include <hip/hip_runtime.h>

// Binarized conv block via i8 MFMA implicit GEMM.
//   a = sign(x+bias1) in {+1,-1} (i8), zero-padded image [32][58][58][256] i8
//   qk = sign(kernel) in {+1,-1} (i8), pre-transposed to W_t[co][k], k=tap*256+ci
//   conv == GEMM: C[pixel][co] = sum_k A_im2col[pixel][k] * W[k][co]
//   out = relu(C*scale[co] + shift[co])   (folded BN + bias2)
// i8 zero-pad == true conv zero-pad -> NO edge corrections (exact integers).
//
// R3-R7 lesson: popcount path is HW-floored at ~143us (v_bcnt ~quarter-rate:
// 72 bcnt/output across 5 structures all land 143-147us). MFMA i8 ceiling is
// 3944 TOPS -> 30us for the 1.18e11-op conv; m97-class structure targets 35-50%.
//
// Staging: global_load_lds(16B) with per-lane GLOBAL src + linear LDS dest;
// bank-conflict fix via chunk-XOR swizzle g(row)=(row>>1)&3 applied to the
// SOURCE address (rule 21: linear dest + inverse-swizzled source + swizzled
// read). Pad zeroing by kernel (hipMemsetAsync breaks under graph replay).

typedef int v4i __attribute__((ext_vector_type(4)));
typedef unsigned int u32;

#define NB   32
#define HW   56
#define HP   58
#define CIN  256
#define COUT 256
#define NPIX (NB*HW*HW)          // 100352
#define KTOT 2304
#define BM   64                  // pixels per block
#define NSTEP 36                 // K steps of 64

#define PA_BYTES ((size_t)NB*HP*HP*CIN)     // 27,557,888
#define WT_OFF   PA_BYTES                   // 64-aligned
#define WT_BYTES ((size_t)KTOT*COUT)        // 589,824
#define SC_OFF   (WT_OFF + WT_BYTES)
#define SH_OFF   (SC_OFF + 1024)

__device__ __forceinline__ void g2l16(const void* g, void* l) {
    __builtin_amdgcn_global_load_lds(
        (const __attribute__((address_space(1))) void*)g,
        (__attribute__((address_space(3))) void*)l, 16, 0, 0);
}

// ---------------- zero the padded i8 activation image ----------------
__global__ __launch_bounds__(256) void zero_pa_kernel(uint4* __restrict__ pa)
{
    pa[(size_t)blockIdx.x * 256 + threadIdx.x] = make_uint4(0, 0, 0, 0);
    // grid = PA_BYTES/16/256 = 6728 exactly
}

// ---------------- pack activations: sign(x + bias1) -> i8 ----------------
__global__ __launch_bounds__(256) void pack_a_kernel(
    const float* __restrict__ x, const float* __restrict__ b1,
    signed char* __restrict__ pa)
{
    const int i4   = blockIdx.x * 256 + threadIdx.x;   // quad index
    const int elem = i4 * 4;
    const int pix  = elem >> 8;
    const int ci   = elem & 255;
    const int n = pix / 3136, r = pix % 3136, h = r / 56, w = r % 56;
    const float4 xv = *(const float4*)(x + elem);
    const float4 bv = *(const float4*)(b1 + ci);
    u32 o = 0;
    o |= (u32)(unsigned char)((xv.x + bv.x >= 0.f) ? 1 : -1);
    o |= (u32)(unsigned char)((xv.y + bv.y >= 0.f) ? 1 : -1) << 8;
    o |= (u32)(unsigned char)((xv.z + bv.z >= 0.f) ? 1 : -1) << 16;
    o |= (u32)(unsigned char)((xv.w + bv.w >= 0.f) ? 1 : -1) << 24;
    *(u32*)(pa + ((size_t)((n * HP + h + 1) * HP + (w + 1))) * CIN + ci) = o;
    // grid = NPIX*CIN/4/256 = 25088
}

// ---------------- pack + transpose weights: W_t[co][k] i8 ----------------
// kernel is (3,3,256,256) fp32 = [k=tap*256+ci][co]; LDS-transpose 64k x 256co.
__global__ __launch_bounds__(256) void packw_kernel(
    const float* __restrict__ k, signed char* __restrict__ wt)
{
    __shared__ signed char tile[64][256];
    const int t = threadIdx.x, k0 = blockIdx.x * 64;
    for (int j = 0; j < 64; ++j)
        tile[j][t] = (k[(size_t)(k0 + j) * COUT + t] >= 0.f) ? 1 : -1;
    __syncthreads();
    u32 wd[16];
#pragma unroll
    for (int j = 0; j < 16; ++j) wd[j] = 0;
#pragma unroll
    for (int j = 0; j < 64; ++j)
        wd[j >> 2] |= ((u32)(unsigned char)tile[j][t]) << ((j & 3) * 8);
    uint4* dst = (uint4*)(wt + (size_t)t * KTOT + k0);
#pragma unroll
    for (int j = 0; j < 4; ++j)
        dst[j] = make_uint4(wd[4*j], wd[4*j+1], wd[4*j+2], wd[4*j+3]);
    // grid = KTOT/64 = 36
}

// ---------------- fold BN + bias2 ----------------
__global__ __launch_bounds__(256) void bnprep_kernel(
    const float* __restrict__ beta, const float* __restrict__ mean,
    const float* __restrict__ var, const float* __restrict__ b2,
    float* __restrict__ scale, float* __restrict__ shift)
{
    const int t = threadIdx.x;
    const float s = rsqrtf(var[t] + 1e-3f);
    scale[t] = s;
    shift[t] = beta[t] - mean[t] * s + b2[t];
}

// ---------------- i8 implicit-GEMM conv + BN + relu ----------------
// block = 256 thr (4 waves); BM=64 pixels x all 256 couts; wave v owns couts
// [v*64, v*64+64). Double-buffered LDS; 16 mfma_i32_16x16x64_i8 per wave/step.
__global__ __launch_bounds__(256, 4) void conv_mfma_kernel(
    const signed char* __restrict__ pa, const signed char* __restrict__ wt,
    const float* __restrict__ scale, const float* __restrict__ shift,
    float* __restrict__ out)
{
    __shared__ signed char Al[2][BM * 64];     // [pixel][k64], swizzled chunks
    __shared__ signed char Bl[2][COUT * 64];   // [co][k64],   swizzled chunks

    const int t = threadIdx.x, l = t & 63, v = t >> 6;
    const int p0 = blockIdx.x * BM;

    // A staging source: thread t stages 16B chunk (t&3) of pixel q = t>>2
    const int q = t >> 2;
    const signed char* abase;
    {
        const int p = p0 + q;
        const int n = p / 3136, r = p % 3136, h = r / 56, w = r % 56;
        const int aswz = (((t & 3) ^ ((q >> 1) & 3)) << 4);  // source pre-swizzle
        abase = pa + ((size_t)(n * HP + h) * HP + w) * CIN + aswz;
    }

    // B staging sources: call j stages (co = v*64 + j*16 + l/4, chunk l&3)
    const signed char* wbase[4];
#pragma unroll
    for (int j = 0; j < 4; ++j) {
        const int co = v * 64 + j * 16 + (l >> 2);
        const int bswz = (((l & 3) ^ ((co >> 1) & 3)) << 4);
        wbase[j] = wt + (size_t)co * KTOT + bswz;
    }

    // fragment ds_read byte offsets (swizzled)
    int aoff[4], boff[4];
#pragma unroll
    for (int pg = 0; pg < 4; ++pg) {
        const int row = pg * 16 + (l & 15);
        aoff[pg] = row * 64 + ((((l >> 4) ^ (row >> 1)) & 3) << 4);
    }
#pragma unroll
    for (int cg = 0; cg < 4; ++cg) {
        const int row = v * 64 + cg * 16 + (l & 15);
        boff[cg] = row * 64 + ((((l >> 4) ^ (row >> 1)) & 3) << 4);
    }

    v4i acc[4][4];
#pragma unroll
    for (int i = 0; i < 4; ++i)
#pragma unroll
        for (int j = 0; j < 4; ++j) acc[i][j] = (v4i){0, 0, 0, 0};

    auto STAGE = [&](int buf, int s) {
        const int tap = s >> 2, cq = s & 3;
        const int ty = tap / 3, tx = tap - ty * 3;
        g2l16(abase + ((ty * HP + tx) << 8) + (cq << 6), &Al[buf][v * 1024]);
#pragma unroll
        for (int j = 0; j < 4; ++j)
            g2l16(wbase[j] + (s << 6), &Bl[buf][v * 4096 + j * 1024]);
    };
    auto COMPUTE = [&](int cur) {
        v4i af[4], bf[4];
#pragma unroll
        for (int pg = 0; pg < 4; ++pg) af[pg] = *(const v4i*)(&Al[cur][aoff[pg]]);
#pragma unroll
        for (int cg = 0; cg < 4; ++cg) bf[cg] = *(const v4i*)(&Bl[cur][boff[cg]]);
#pragma unroll
        for (int pg = 0; pg < 4; ++pg)
#pragma unroll
            for (int cg = 0; cg < 4; ++cg)
                acc[pg][cg] = __builtin_amdgcn_mfma_i32_16x16x64_i8(
                    af[pg], bf[cg], acc[pg][cg], 0, 0, 0);
    };

    STAGE(0, 0);
    for (int sp = 0; sp < NSTEP / 2; ++sp) {
        const int s0 = 2 * sp;
        STAGE(1, s0 + 1);                      // prefetch next into buf1
        asm volatile("s_waitcnt vmcnt(0)" ::: "memory");
        __syncthreads();                       // buf0 loads visible to all
        COMPUTE(0);
        __syncthreads();                       // everyone done reading buf0
        if (s0 + 2 < NSTEP) STAGE(0, s0 + 2);  // prefetch into buf0
        asm volatile("s_waitcnt vmcnt(0)" ::: "memory");
        __syncthreads();
        COMPUTE(1);
        __syncthreads();
    }

    // epilogue: C row = (l>>4)*4 + reg (pixel), col = l&15 (co)  [m89 layout]
#pragma unroll
    for (int cg = 0; cg < 4; ++cg) {
        const int co = v * 64 + cg * 16 + (l & 15);
        const float sc = scale[co], sh = shift[co];
#pragma unroll
        for (int pg = 0; pg < 4; ++pg) {
            const int prow0 = p0 + pg * 16 + (l >> 4) * 4;
#pragma unroll
            for (int rr = 0; rr < 4; ++rr) {
                const float y = (float)acc[pg][cg][rr];
                out[(size_t)(prow0 + rr) * COUT + co] = fmaxf(fmaf(y, sc, sh), 0.f);
            }
        }
    }
}

extern "C" void kernel_launch(void* const* d_in, const int* in_sizes, int n_in,
                              void* d_out, int out_size, void* d_ws, size_t ws_size,
                              hipStream_t stream)
{
    const float* x      = (const float*)d_in[0];
    const float* bias1  = (const float*)d_in[1];
    const float* kernel = (const float*)d_in[2];
    const float* bn_beta = (const float*)d_in[3];
    const float* bn_mean = (const float*)d_in[4];
    const float* bn_var  = (const float*)d_in[5];
    const float* bias2   = (const float*)d_in[6];
    float* out = (float*)d_out;

    signed char* pa = (signed char*)d_ws;                 // padded i8 image
    signed char* wtp = (signed char*)d_ws + WT_OFF;       // W_t[co][k]
    float* scale = (float*)((char*)d_ws + SC_OFF);
    float* shift = (float*)((char*)d_ws + SH_OFF);

    zero_pa_kernel<<<dim3((int)(PA_BYTES / 16 / 256)), dim3(256), 0, stream>>>((uint4*)pa);
    pack_a_kernel<<<dim3(NPIX * CIN / 4 / 256), dim3(256), 0, stream>>>(x, bias1, pa);
    packw_kernel<<<dim3(KTOT / 64), dim3(256), 0, stream>>>(kernel, wtp);
    bnprep_kernel<<<dim3(1), dim3(256), 0, stream>>>(bn_beta, bn_mean, bn_var, bias2,
                                                     scale, shift);
    conv_mfma_kernel<<<dim3(NPIX / BM), dim3(256), 0, stream>>>(pa, wtp, scale, shift, out);
}

// Round 9
// 114.356 us; speedup vs baseline: 1.4848x; 1.1865x over previous
//
#include <hip/hip_runtime.h>

// Binarized conv block via i8 MFMA implicit GEMM.
//   a = sign(x+bias1) in {+1,-1} (i8), zero-padded image [32][58][58][256] i8
//   qk = sign(kernel) in {+1,-1} (i8), pre-transposed to W_t[co][k]
//   conv == GEMM: C[pixel][co] = sum_k A_im2col[pixel][k] * W[k][co]
//   out = relu(C*scale[co] + shift[co])   (folded BN + bias2)
// i8 zero-pad == true conv zero-pad -> exact integers, no edge corrections.
//
// R8 -> R9: R8's loop did STAGE(next); vmcnt(0); barrier; COMPUTE(cur) — the
// drain serialized prefetch latency with compute TWICE per K-step (MfmaUtil
// 23%). R9: STAGE(next); COMPUTE(cur); __syncthreads() — one drain per step,
// latency hidden under 32 MFMAs. BM 64->128 (more MFMA per drain, half the
// B-panel L2 traffic). zero_pa fused into pack_a (borders write 0 directly;
// hipMemsetAsync is unusable: it didn't take effect under graph replay).

typedef int v4i __attribute__((ext_vector_type(4)));
typedef unsigned int u32;

#define NB   32
#define HW   56
#define HP   58
#define HP2  (HP*HP)             // 3364
#define CIN  256
#define COUT 256
#define NPIX (NB*HW*HW)          // 100352
#define KTOT 2304
#define BM   128                 // pixels per block
#define NSTEP 36                 // K steps of 64

#define PA_BYTES ((size_t)NB*HP*HP*CIN)     // 27,557,888
#define WT_OFF   PA_BYTES
#define WT_BYTES ((size_t)KTOT*COUT)        // 589,824
#define SC_OFF   (WT_OFF + WT_BYTES)
#define SH_OFF   (SC_OFF + 1024)

__device__ __forceinline__ void g2l16(const void* g, void* l) {
    __builtin_amdgcn_global_load_lds(
        (const __attribute__((address_space(1))) void*)g,
        (__attribute__((address_space(3))) void*)l, 16, 0, 0);
}

// ------- pack activations incl. pad ring: sign(x+bias1) or 0 -> i8 -------
// one wave per padded pixel (64 lanes x 4 channels); border pixels write 0.
__global__ __launch_bounds__(256) void pack_a_kernel(
    const float* __restrict__ x, const float* __restrict__ b1,
    signed char* __restrict__ pa)
{
    const int lane = threadIdx.x & 63;
    const int pp = blockIdx.x * 4 + (threadIdx.x >> 6);   // padded pixel
    const int n = pp / HP2, r = pp % HP2, ph = r / HP, pw = r % HP;
    const int ci = lane * 4;
    u32 o = 0;
    if (ph >= 1 && ph <= HW && pw >= 1 && pw <= HW) {     // wave-uniform branch
        const int pix = (n * HW + ph - 1) * HW + (pw - 1);
        const float4 xv = *(const float4*)(x + (size_t)pix * CIN + ci);
        const float4 bv = *(const float4*)(b1 + ci);
        o  = (u32)(unsigned char)((xv.x + bv.x >= 0.f) ? 1 : -1);
        o |= (u32)(unsigned char)((xv.y + bv.y >= 0.f) ? 1 : -1) << 8;
        o |= (u32)(unsigned char)((xv.z + bv.z >= 0.f) ? 1 : -1) << 16;
        o |= (u32)(unsigned char)((xv.w + bv.w >= 0.f) ? 1 : -1) << 24;
    }
    *(u32*)(pa + (size_t)pp * CIN + ci) = o;
    // grid = NB*HP*HP/4 = 26912
}

// ---------------- pack + transpose weights: W_t[co][k] i8 ----------------
__global__ __launch_bounds__(256) void packw_kernel(
    const float* __restrict__ k, signed char* __restrict__ wt)
{
    __shared__ signed char tile[64][256];
    const int t = threadIdx.x, k0 = blockIdx.x * 64;
    for (int j = 0; j < 64; ++j)
        tile[j][t] = (k[(size_t)(k0 + j) * COUT + t] >= 0.f) ? 1 : -1;
    __syncthreads();
    u32 wd[16];
#pragma unroll
    for (int j = 0; j < 16; ++j) wd[j] = 0;
#pragma unroll
    for (int j = 0; j < 64; ++j)
        wd[j >> 2] |= ((u32)(unsigned char)tile[j][t]) << ((j & 3) * 8);
    uint4* dst = (uint4*)(wt + (size_t)t * KTOT + k0);
#pragma unroll
    for (int j = 0; j < 4; ++j)
        dst[j] = make_uint4(wd[4*j], wd[4*j+1], wd[4*j+2], wd[4*j+3]);
    // grid = KTOT/64 = 36
}

// ---------------- fold BN + bias2 ----------------
__global__ __launch_bounds__(256) void bnprep_kernel(
    const float* __restrict__ beta, const float* __restrict__ mean,
    const float* __restrict__ var, const float* __restrict__ b2,
    float* __restrict__ scale, float* __restrict__ shift)
{
    const int t = threadIdx.x;
    const float s = rsqrtf(var[t] + 1e-3f);
    scale[t] = s;
    shift[t] = beta[t] - mean[t] * s + b2[t];
}

// ---------------- i8 implicit-GEMM conv + BN + relu ----------------
// 256 thr (4 waves); BM=128 pixels x 256 couts; wave v owns all 128 pixels x
// couts [v*64, v*64+64): acc[8][4], 32 mfma_i32_16x16x64_i8 per step.
__global__ __launch_bounds__(256, 2) void conv_mfma_kernel(
    const signed char* __restrict__ pa, const signed char* __restrict__ wt,
    const float* __restrict__ scale, const float* __restrict__ shift,
    float* __restrict__ out)
{
    __shared__ signed char Al[2][BM * 64];     // 2 x 8 KB, [pixel][k64] chunks
    __shared__ signed char Bl[2][COUT * 64];   // 2 x 16 KB, [co][k64] chunks

    const int t = threadIdx.x, l = t & 63, v = t >> 6;
    const int p0 = blockIdx.x * BM;

    // A staging: thread t stages chunk (t&3) of pixels q and q+64 (q = t>>2)
    const signed char* abase[2];
#pragma unroll
    for (int i = 0; i < 2; ++i) {
        const int q = (t >> 2) + i * 64;
        const int p = p0 + q;
        const int n = p / 3136, r = p % 3136, h = r / 56, w = r % 56;
        const int aswz = (((t & 3) ^ ((q >> 1) & 3)) << 4);  // source pre-swizzle
        abase[i] = pa + ((size_t)(n * HP + h) * HP + w) * CIN + aswz;
    }

    // B staging: call j stages (co = v*64 + j*16 + l/4, chunk l&3)
    const signed char* wbase[4];
#pragma unroll
    for (int j = 0; j < 4; ++j) {
        const int co = v * 64 + j * 16 + (l >> 2);
        const int bswz = (((l & 3) ^ ((co >> 1) & 3)) << 4);
        wbase[j] = wt + (size_t)co * KTOT + bswz;
    }

    // fragment ds_read byte offsets (swizzled reads matching pre-swizzled src)
    int aoff[8], boff[4];
#pragma unroll
    for (int pg = 0; pg < 8; ++pg) {
        const int row = pg * 16 + (l & 15);
        aoff[pg] = row * 64 + ((((l >> 4) ^ (row >> 1)) & 3) << 4);
    }
#pragma unroll
    for (int cg = 0; cg < 4; ++cg) {
        const int row = v * 64 + cg * 16 + (l & 15);
        boff[cg] = row * 64 + ((((l >> 4) ^ (row >> 1)) & 3) << 4);
    }

    v4i acc[8][4];
#pragma unroll
    for (int i = 0; i < 8; ++i)
#pragma unroll
        for (int j = 0; j < 4; ++j) acc[i][j] = (v4i){0, 0, 0, 0};

    auto STAGE = [&](int buf, int s) {
        const int tap = s >> 2, cq = s & 3;
        const int ty = tap / 3, tx = tap - ty * 3;
        const int goff = ((ty * HP + tx) << 8) + (cq << 6);
        g2l16(abase[0] + goff, &Al[buf][v * 1024]);
        g2l16(abase[1] + goff, &Al[buf][4096 + v * 1024]);
#pragma unroll
        for (int j = 0; j < 4; ++j)
            g2l16(wbase[j] + (s << 6), &Bl[buf][v * 4096 + j * 1024]);
    };
    auto COMPUTE = [&](int cur) {
        v4i af[8], bf[4];
#pragma unroll
        for (int pg = 0; pg < 8; ++pg) af[pg] = *(const v4i*)(&Al[cur][aoff[pg]]);
#pragma unroll
        for (int cg = 0; cg < 4; ++cg) bf[cg] = *(const v4i*)(&Bl[cur][boff[cg]]);
#pragma unroll
        for (int pg = 0; pg < 8; ++pg)
#pragma unroll
            for (int cg = 0; cg < 4; ++cg)
                acc[pg][cg] = __builtin_amdgcn_mfma_i32_16x16x64_i8(
                    af[pg], bf[cg], acc[pg][cg], 0, 0, 0);
    };

    STAGE(0, 0);
    __syncthreads();                           // drains vmcnt -> buf0 ready
#pragma unroll 2
    for (int s = 0; s < NSTEP; ++s) {
        if (s + 1 < NSTEP) STAGE((s + 1) & 1, s + 1);  // issue next-tile loads
        COMPUTE(s & 1);                                 // overlap their latency
        __syncthreads();    // vmcnt(0): next tile landed; all reads of cur done
    }

    // epilogue: C col = l&15 (co), row = (l>>4)*4 + reg (pixel)   [m89 layout]
#pragma unroll
    for (int cg = 0; cg < 4; ++cg) {
        const int co = v * 64 + cg * 16 + (l & 15);
        const float sc = scale[co], sh = shift[co];
#pragma unroll
        for (int pg = 0; pg < 8; ++pg) {
            const int prow0 = p0 + pg * 16 + (l >> 4) * 4;
#pragma unroll
            for (int rr = 0; rr < 4; ++rr) {
                const float y = (float)acc[pg][cg][rr];
                out[(size_t)(prow0 + rr) * COUT + co] = fmaxf(fmaf(y, sc, sh), 0.f);
            }
        }
    }
}

extern "C" void kernel_launch(void* const* d_in, const int* in_sizes, int n_in,
                              void* d_out, int out_size, void* d_ws, size_t ws_size,
                              hipStream_t stream)
{
    const float* x      = (const float*)d_in[0];
    const float* bias1  = (const float*)d_in[1];
    const float* kernel = (const float*)d_in[2];
    const float* bn_beta = (const float*)d_in[3];
    const float* bn_mean = (const float*)d_in[4];
    const float* bn_var  = (const float*)d_in[5];
    const float* bias2   = (const float*)d_in[6];
    float* out = (float*)d_out;

    signed char* pa  = (signed char*)d_ws;                // padded i8 image
    signed char* wtp = (signed char*)d_ws + WT_OFF;       // W_t[co][k]
    float* scale = (float*)((char*)d_ws + SC_OFF);
    float* shift = (float*)((char*)d_ws + SH_OFF);

    pack_a_kernel<<<dim3(NB * HP2 / 4), dim3(256), 0, stream>>>(x, bias1, pa);
    packw_kernel<<<dim3(KTOT / 64), dim3(256), 0, stream>>>(kernel, wtp);
    bnprep_kernel<<<dim3(1), dim3(256), 0, stream>>>(bn_beta, bn_mean, bn_var, bias2,
                                                     scale, shift);
    conv_mfma_kernel<<<dim3(NPIX / BM), dim3(256), 0, stream>>>(pa, wtp, scale, shift, out);
}